// Round 6
// baseline (280.801 us; speedup 1.0000x reference)
//
#include <hip/hip_runtime.h>

#define E_DIM 1024
#define NH 16
#define DH 64
#define BSEG 8
#define LQ 512
#define LKV 1024

typedef short bf16x8 __attribute__((ext_vector_type(8)));
typedef float f32x4 __attribute__((ext_vector_type(4)));
typedef unsigned short u16;

// round-to-nearest-even fp32 -> bf16 bits
__device__ __forceinline__ u16 f2bf(float x) {
    unsigned u = __float_as_uint(x);
    u += 0x7FFF + ((u >> 16) & 1);
    return (u16)(u >> 16);
}

// async global->LDS, 16B per lane; lds dest wave-uniform base + lane*16
__device__ __forceinline__ void async16(const void* g, const void* l) {
    __builtin_amdgcn_global_load_lds(
        (const __attribute__((address_space(1))) unsigned int*)g,
        (__attribute__((address_space(3))) unsigned int*)l, 16, 0, 0);
}

// ---------------------------------------------------------------------------
// Fused fp32->bf16 convert for all 4 inputs (one launch).
// ---------------------------------------------------------------------------
__global__ __launch_bounds__(256) void cvt_all_kernel(
    const float* __restrict__ inputs, const float* __restrict__ queries,
    const float* __restrict__ w_in, const float* __restrict__ w_out,
    u16* __restrict__ ib, u16* __restrict__ qb,
    u16* __restrict__ wib, u16* __restrict__ wob)
{
    int blk = blockIdx.x;
    const float* s; u16* d; int base;
    if (blk < 8192)        { s = inputs;  d = ib;  base = blk; }
    else if (blk < 12288)  { s = queries; d = qb;  base = blk - 8192; }
    else if (blk < 15360)  { s = w_in;    d = wib; base = blk - 12288; }
    else                   { s = w_out;   d = wob; base = blk - 15360; }
    int i = base * 256 + threadIdx.x;
    float4 v = ((const float4*)s)[i];
    ushort4 o;
    o.x = f2bf(v.x); o.y = f2bf(v.y); o.z = f2bf(v.z); o.w = f2bf(v.w);
    ((ushort4*)d)[i] = o;
}

// ---------------------------------------------------------------------------
// Fused Q/K/V projection GEMM v2. 128x256 tile, BK=32, 256 threads (4 waves),
// 64x128 per-wave register block (af[4] x wf[8] -> 32 MFMA / 12 KB LDS read).
// 1D grid 640, XCD-compact: xcd = bid&7 owns a by-strip; bx slow within.
//   KV (bid<512): by = xcd*8 + (i&7), bx = i>>3 (i=bid>>3); A=inputs_b,
//     W=w_in rows [1024,3072), N=2048. bx<4 -> Kf (frag16), bx>=4 -> Vf.
//   Q (bid>=512): by = xcd*4 + (i&3), bx = i>>2; A=queries_b, W=w_in[0:1024).
// Layouts (unchanged from r5):
//   Qf/Kf "frag16": chunk per (t=tok>>4, h), 1024 shorts; (token=16t+tc, d)
//     at (d>>3)*128 + tc*8 + (d&7).
//   Vf "sigma'-frag": chunk per (g32=tok>>5, h), 2048 shorts; (token=
//     32*g32+sigma'(8q+j), d) at ((td*4+q)*16 + (d&15))*8 + j, td=(d&63)>>4.
// ---------------------------------------------------------------------------
__global__ __launch_bounds__(256) void proj_gemm_kernel(
    const u16* __restrict__ inputs_b, const u16* __restrict__ queries_b,
    const u16* __restrict__ w_in_b, const float* __restrict__ b_in,
    u16* __restrict__ Kf, u16* __restrict__ Qf, u16* __restrict__ Vf)
{
    __shared__ u16 As[128 * 32];   //  8 KB: 8 chunks
    __shared__ u16 Ws[256 * 32];   // 16 KB: 16 chunks

    const int bid = blockIdx.x;
    const bool isQ = (bid >= 512);
    const int x = bid & 7;
    int bx, by;
    if (!isQ) { int i = bid >> 3;         bx = i >> 3; by = x * 8 + (i & 7); }
    else      { int i = (bid - 512) >> 3; bx = i >> 2; by = x * 4 + (i & 3); }

    const u16* A = isQ ? queries_b : inputs_b;
    const u16* W = w_in_b + (isQ ? 0 : (size_t)E_DIM * E_DIM);
    const float* bias = b_in + (isQ ? 0 : E_DIM);
    const int m_blk = by * 128;
    const int n_blk = bx * 256;
    const int K = E_DIM;

    const int tid = threadIdx.x;
    const int l = tid & 63;
    const int w = tid >> 6;
    const int m0 = (w & 1) * 64;      // 0 / 64
    const int n0 = (w >> 1) * 128;    // 0 / 128
    const int quad = l >> 4;
    const int c = l & 15;

    f32x4 acc[4][8];
    #pragma unroll
    for (int i = 0; i < 4; ++i)
        #pragma unroll
        for (int j = 0; j < 8; ++j)
            acc[i][j] = (f32x4){0.f, 0.f, 0.f, 0.f};

    const int srow = l >> 2;
    const int skoff = (l & 3) * 8;
    // staging: A 8 chunks (wave: w, w+4); W 16 chunks (wave: w,w+4,w+8,w+12)
    const u16* AgA = A + (size_t)(m_blk + w * 16 + srow) * K + skoff;
    const u16* AgB = A + (size_t)(m_blk + (w + 4) * 16 + srow) * K + skoff;
    const u16* Wg0 = W + (size_t)(n_blk + w * 16 + srow) * K + skoff;
    const u16* Wg1 = W + (size_t)(n_blk + (w + 4) * 16 + srow) * K + skoff;
    const u16* Wg2 = W + (size_t)(n_blk + (w + 8) * 16 + srow) * K + skoff;
    const u16* Wg3 = W + (size_t)(n_blk + (w + 12) * 16 + srow) * K + skoff;

    for (int k0 = 0; k0 < K; k0 += 32) {
        __syncthreads();
        async16(AgA + k0, As + (size_t)w * 512);
        async16(AgB + k0, As + (size_t)(w + 4) * 512);
        async16(Wg0 + k0, Ws + (size_t)w * 512);
        async16(Wg1 + k0, Ws + (size_t)(w + 4) * 512);
        async16(Wg2 + k0, Ws + (size_t)(w + 8) * 512);
        async16(Wg3 + k0, Ws + (size_t)(w + 12) * 512);
        __syncthreads();

        bf16x8 af[4], wf[8];
        #pragma unroll
        for (int t = 0; t < 4; ++t)
            af[t] = *(const bf16x8*)&As[((m0 >> 4) + t) * 512 + c * 32 + quad * 8];
        #pragma unroll
        for (int t = 0; t < 8; ++t)
            wf[t] = *(const bf16x8*)&Ws[((n0 >> 4) + t) * 512 + c * 32 + quad * 8];
        #pragma unroll
        for (int i = 0; i < 4; ++i)
            #pragma unroll
            for (int j = 0; j < 8; ++j)
                acc[i][j] = __builtin_amdgcn_mfma_f32_16x16x32_bf16(
                    af[i], wf[j], acc[i][j], 0, 0, 0);
    }

    #pragma unroll
    for (int jj = 0; jj < 8; ++jj) {
        int col = n_blk + n0 + jj * 16 + c;
        float bv = bias[col];
        if (isQ || col < 1024) {
            u16* dst = isQ ? Qf : Kf;
            int hh = col >> 6, d = col & 63;
            int dq = d >> 3, dj = d & 7;
            #pragma unroll
            for (int i = 0; i < 4; ++i) {
                int t = (m_blk + m0 + i * 16) >> 4;
                size_t base = ((size_t)(t * NH + hh)) * 1024
                            + (size_t)(dq * 16 + quad * 4) * 8 + dj;
                #pragma unroll
                for (int r = 0; r < 4; ++r)
                    dst[base + (size_t)r * 8] = f2bf(acc[i][jj][r] + bv);
            }
        } else {
            int vcol = col - 1024;
            int hv = vcol >> 6, d = vcol & 63;
            int td = d >> 4, ct = d & 15;
            #pragma unroll
            for (int i = 0; i < 4; ++i) {
                int tok = m_blk + m0 + i * 16;
                int g32 = tok >> 5;
                int jo = (tok & 16) >> 2;          // 0 or 4
                ushort4 pk;
                pk.x = f2bf(acc[i][jj][0] + bv);
                pk.y = f2bf(acc[i][jj][1] + bv);
                pk.z = f2bf(acc[i][jj][2] + bv);
                pk.w = f2bf(acc[i][jj][3] + bv);
                *(ushort4*)(Vf + ((size_t)(g32 * NH + hv)) * 2048
                            + (size_t)((td * 4 + quad) * 16 + ct) * 8 + jo) = pk;
            }
        }
    }
}

// ---------------------------------------------------------------------------
// Attention, S^T formulation; frag-ordered operands; no LDS/barriers.
// 1D grid 1024: bid = qt*128 + b*16 + h  -> bid%8 = h%8: all 8 q-tiles of a
// given (b,h) share one XCD (L2 reuse of K/V). 256 thr = 4 waves x 16 q rows.
// K/V frags register-double-buffered to hide global latency behind softmax.
// ---------------------------------------------------------------------------
struct KVfrags { bf16x8 kf[4][2]; bf16x8 vf[2][4]; };

__global__ __launch_bounds__(256) void attn_kernel(
    const u16* __restrict__ Qf, const u16* __restrict__ Kf,
    const u16* __restrict__ Vf, u16* __restrict__ Ob)
{
    const int tid = threadIdx.x;
    const int l = tid & 63;
    const int w = tid >> 6;
    const int quad = l >> 4;
    const int c = l & 15;
    const int bid = blockIdx.x;
    const int h = bid & 15;
    const int b = (bid >> 4) & 7;
    const int qt = bid >> 7;
    const int q0 = b * LQ + qt * 64 + w * 16;
    const float C1 = 0.18033688011112042f;   // (1/8)*log2(e)

    // Q B-frags (frag16 layout: fully coalesced)
    bf16x8 qf[2];
    {
        size_t qb = ((size_t)((q0 >> 4) * NH + h)) * 1024 + (size_t)l * 8;
        qf[0] = *(const bf16x8*)(Qf + qb);
        qf[1] = *(const bf16x8*)(Qf + qb + 512);
    }

    f32x4 o[4];
    #pragma unroll
    for (int td = 0; td < 4; ++td) o[td] = (f32x4){0.f, 0.f, 0.f, 0.f};
    float m_i = -1e30f, l_i = 0.f;

    auto load_kv = [&](int kv0, KVfrags& dst) {
        const int kvg = b * LKV + kv0;
        #pragma unroll
        for (int nt = 0; nt < 4; ++nt) {
            size_t kb = ((size_t)((((kvg >> 4) + nt) * NH) + h)) * 1024 + (size_t)l * 8;
            dst.kf[nt][0] = *(const bf16x8*)(Kf + kb);
            dst.kf[nt][1] = *(const bf16x8*)(Kf + kb + 512);
        }
        #pragma unroll
        for (int g = 0; g < 2; ++g) {
            size_t vb = ((size_t)((((kvg >> 5) + g) * NH) + h)) * 2048 + (size_t)l * 8;
            #pragma unroll
            for (int td = 0; td < 4; ++td)
                dst.vf[g][td] = *(const bf16x8*)(Vf + vb + td * 512);
        }
    };

    auto step = [&](KVfrags& cv) {
        // S^T = K · Q^T (4 kv-tiles of 16)
        f32x4 s[4];
        #pragma unroll
        for (int nt = 0; nt < 4; ++nt) s[nt] = (f32x4){0.f, 0.f, 0.f, 0.f};
        #pragma unroll
        for (int nt = 0; nt < 4; ++nt)
            #pragma unroll
            for (int hk = 0; hk < 2; ++hk)
                s[nt] = __builtin_amdgcn_mfma_f32_16x16x32_bf16(
                    cv.kf[nt][hk], qf[hk], s[nt], 0, 0, 0);

        // online softmax; lane state belongs to q = q0 + c (replicated / quads)
        float vm = -1e30f;
        #pragma unroll
        for (int nt = 0; nt < 4; ++nt)
            #pragma unroll
            for (int r = 0; r < 4; ++r) vm = fmaxf(vm, s[nt][r]);
        vm = fmaxf(vm, __shfl_xor(vm, 16, 64));
        vm = fmaxf(vm, __shfl_xor(vm, 32, 64));
        float mnew = fmaxf(m_i, vm);
        float alpha = __builtin_amdgcn_exp2f((m_i - mnew) * C1);
        m_i = mnew;

        float p[4][4];
        float rs = 0.f;
        #pragma unroll
        for (int nt = 0; nt < 4; ++nt)
            #pragma unroll
            for (int r = 0; r < 4; ++r) {
                p[nt][r] = __builtin_amdgcn_exp2f((s[nt][r] - mnew) * C1);
                rs += p[nt][r];
            }
        rs += __shfl_xor(rs, 16, 64);
        rs += __shfl_xor(rs, 32, 64);
        l_i = l_i * alpha + rs;

        // rescale O (O rows are q = quad*4+r; alpha lives at lane q = c)
        float ar[4];
        #pragma unroll
        for (int r = 0; r < 4; ++r) ar[r] = __shfl(alpha, quad * 4 + r, 16);
        #pragma unroll
        for (int td = 0; td < 4; ++td)
            #pragma unroll
            for (int r = 0; r < 4; ++r) o[td][r] *= ar[r];

        // A-frags for PV: sigma' puts the lane's own p regs in place
        bf16x8 af[2];
        #pragma unroll
        for (int g = 0; g < 2; ++g)
            #pragma unroll
            for (int r = 0; r < 4; ++r) {
                af[g][r]     = (short)f2bf(p[2 * g][r]);
                af[g][4 + r] = (short)f2bf(p[2 * g + 1][r]);
            }

        #pragma unroll
        for (int g = 0; g < 2; ++g)
            #pragma unroll
            for (int td = 0; td < 4; ++td)
                o[td] = __builtin_amdgcn_mfma_f32_16x16x32_bf16(
                    af[g], cv.vf[g][td], o[td], 0, 0, 0);
    };

    // software-pipelined: prefetch next 64-kv chunk while computing current
    KVfrags bufA, bufB;
    load_kv(0, bufA);
    #pragma unroll
    for (int it = 0; it < 16; it += 2) {
        if (it + 1 < 16) load_kv((it + 1) * 64, bufB);
        step(bufA);
        if (it + 2 < 16) load_kv((it + 2) * 64, bufA);
        if (it + 1 < 16) step(bufB);
    }

    // epilogue: normalize (l_i lives at lane q=c; O rows are q=quad*4+r)
    float invl = 1.f / l_i;
    float ir[4];
    #pragma unroll
    for (int r = 0; r < 4; ++r) ir[r] = __shfl(invl, quad * 4 + r, 16);
    #pragma unroll
    for (int td = 0; td < 4; ++td)
        #pragma unroll
        for (int r = 0; r < 4; ++r)
            Ob[(size_t)(q0 + quad * 4 + r) * E_DIM + h * 64 + td * 16 + c] =
                f2bf(o[td][r] * ir[r]);
}

// ---------------------------------------------------------------------------
// Output projection: out[4096,1024] = Ob @ w_out^T + b_out (fp32 out).
// 1D grid 256, XCD-compact: xcd = bid&7 -> by strip of 4, bx slow.
// ---------------------------------------------------------------------------
__global__ __launch_bounds__(256) void out_gemm_kernel(
    const u16* __restrict__ A, const u16* __restrict__ W,
    const float* __restrict__ bias, float* __restrict__ Cf)
{
    __shared__ u16 As[128 * 32];
    __shared__ u16 Ws[128 * 32];

    const int K = E_DIM, N = E_DIM;
    const int bid = blockIdx.x;
    const int x = bid & 7;
    const int i_ = bid >> 3;            // 0..31
    const int m_blk = (x * 4 + (i_ & 3)) * 128;
    const int n_blk = (i_ >> 2) * 128;

    const int tid = threadIdx.x;
    const int l = tid & 63;
    const int w = tid >> 6;
    const int m0 = (w & 1) * 64;
    const int n0 = (w >> 1) * 64;
    const int quad = l >> 4;
    const int c = l & 15;

    f32x4 acc[4][4];
    #pragma unroll
    for (int i = 0; i < 4; ++i)
        #pragma unroll
        for (int j = 0; j < 4; ++j)
            acc[i][j] = (f32x4){0.f, 0.f, 0.f, 0.f};

    const int srow = l >> 2;
    const int skoff = (l & 3) * 8;
    const u16* Ag1 = A + (size_t)(m_blk + w * 16 + srow) * K + skoff;
    const u16* Ag2 = A + (size_t)(m_blk + (w + 4) * 16 + srow) * K + skoff;
    const u16* Wg1 = W + (size_t)(n_blk + w * 16 + srow) * K + skoff;
    const u16* Wg2 = W + (size_t)(n_blk + (w + 4) * 16 + srow) * K + skoff;

    for (int k0 = 0; k0 < K; k0 += 32) {
        __syncthreads();
        async16(Ag1 + k0, As + (size_t)w * 512);
        async16(Ag2 + k0, As + (size_t)(w + 4) * 512);
        async16(Wg1 + k0, Ws + (size_t)w * 512);
        async16(Wg2 + k0, Ws + (size_t)(w + 4) * 512);
        __syncthreads();

        bf16x8 af[4], wf[4];
        #pragma unroll
        for (int t = 0; t < 4; ++t) {
            af[t] = *(const bf16x8*)&As[(m0 + t * 16 + c) * 32 + quad * 8];
            wf[t] = *(const bf16x8*)&Ws[(n0 + t * 16 + c) * 32 + quad * 8];
        }
        #pragma unroll
        for (int i = 0; i < 4; ++i)
            #pragma unroll
            for (int j = 0; j < 4; ++j)
                acc[i][j] = __builtin_amdgcn_mfma_f32_16x16x32_bf16(
                    af[i], wf[j], acc[i][j], 0, 0, 0);
    }

    #pragma unroll
    for (int j = 0; j < 4; ++j) {
        int col = n_blk + n0 + j * 16 + c;
        float bv = bias[col];
        #pragma unroll
        for (int i = 0; i < 4; ++i) {
            int row = m_blk + m0 + i * 16 + quad * 4;
            #pragma unroll
            for (int r = 0; r < 4; ++r)
                Cf[(size_t)(row + r) * N + col] = acc[i][j][r] + bv;
        }
    }
}

// ---------------------------------------------------------------------------
extern "C" void kernel_launch(void* const* d_in, const int* in_sizes, int n_in,
                              void* d_out, int out_size, void* d_ws, size_t ws_size,
                              hipStream_t stream) {
    const float* inputs  = (const float*)d_in[0];   // [8192,1024]
    const float* queries = (const float*)d_in[1];   // [4096,1024]
    const float* w_in    = (const float*)d_in[2];   // [3072,1024]
    const float* b_in    = (const float*)d_in[3];   // [3072]
    const float* w_out   = (const float*)d_in[4];   // [1024,1024]
    const float* b_out   = (const float*)d_in[5];   // [1024]
    float* out = (float*)d_out;                     // [4096,1024] fp32

    const int NQ = BSEG * LQ;    // 4096
    const int NKV = BSEG * LKV;  // 8192

    // workspace: 80 MB
    u16* inputs_b  = (u16*)d_ws;                                   // 16 MB
    u16* queries_b = inputs_b  + (size_t)NKV * E_DIM;              //  8 MB
    u16* w_in_b    = queries_b + (size_t)NQ * E_DIM;               //  6 MB
    u16* w_out_b   = w_in_b    + (size_t)3 * E_DIM * E_DIM;        //  2 MB
    u16* Qf        = w_out_b   + (size_t)E_DIM * E_DIM;            //  8 MB
    u16* Kf        = Qf        + (size_t)NQ * E_DIM;               // 16 MB
    u16* Vf        = Kf        + (size_t)NKV * E_DIM;              // 16 MB
    u16* Ob        = Vf        + (size_t)NKV * E_DIM;              //  8 MB

    dim3 blk(256);

    cvt_all_kernel<<<16384, blk, 0, stream>>>(
        inputs, queries, w_in, w_out, inputs_b, queries_b, w_in_b, w_out_b);

    proj_gemm_kernel<<<640, blk, 0, stream>>>(
        inputs_b, queries_b, w_in_b, b_in, Kf, Qf, Vf);

    attn_kernel<<<1024, blk, 0, stream>>>(Qf, Kf, Vf, Ob);

    out_gemm_kernel<<<256, blk, 0, stream>>>(
        Ob, w_out_b, b_out, out);
}

// Round 7
// 240.821 us; speedup vs baseline: 1.1660x; 1.1660x over previous
//
#include <hip/hip_runtime.h>

#define E_DIM 1024
#define NH 16
#define DH 64
#define BSEG 8
#define LQ 512
#define LKV 1024

typedef short bf16x8 __attribute__((ext_vector_type(8)));
typedef float f32x4 __attribute__((ext_vector_type(4)));
typedef unsigned short u16;

// round-to-nearest-even fp32 -> bf16 bits
__device__ __forceinline__ u16 f2bf(float x) {
    unsigned u = __float_as_uint(x);
    u += 0x7FFF + ((u >> 16) & 1);
    return (u16)(u >> 16);
}

// async global->LDS, 16B per lane; lds dest wave-uniform base + lane*16
__device__ __forceinline__ void async16(const void* g, const void* l) {
    __builtin_amdgcn_global_load_lds(
        (const __attribute__((address_space(1))) unsigned int*)g,
        (__attribute__((address_space(3))) unsigned int*)l, 16, 0, 0);
}

// ---------------------------------------------------------------------------
// Fused fp32->bf16 convert for all 4 inputs (one launch).
// ---------------------------------------------------------------------------
__global__ __launch_bounds__(256) void cvt_all_kernel(
    const float* __restrict__ inputs, const float* __restrict__ queries,
    const float* __restrict__ w_in, const float* __restrict__ w_out,
    u16* __restrict__ ib, u16* __restrict__ qb,
    u16* __restrict__ wib, u16* __restrict__ wob)
{
    int blk = blockIdx.x;
    const float* s; u16* d; int base;
    if (blk < 8192)        { s = inputs;  d = ib;  base = blk; }
    else if (blk < 12288)  { s = queries; d = qb;  base = blk - 8192; }
    else if (blk < 15360)  { s = w_in;    d = wib; base = blk - 12288; }
    else                   { s = w_out;   d = wob; base = blk - 15360; }
    int i = base * 256 + threadIdx.x;
    float4 v = ((const float4*)s)[i];
    ushort4 o;
    o.x = f2bf(v.x); o.y = f2bf(v.y); o.z = f2bf(v.z); o.w = f2bf(v.w);
    ((ushort4*)d)[i] = o;
}

// ---------------------------------------------------------------------------
// Fused Q/K/V projection GEMM. 128x128 tile (r5 structure: 108 VGPR, 4 waves
// x 64x64), BK=32, 256 threads — plus r6's XCD-compact 1D grid (fetch fix).
// Grid 1280: KV bid<1024: xcd=bid&7, i=bid>>3, bx=i>>3 (0..15, slow),
//   by=xcd*8+(i&7); A=inputs_b, W=w_in rows [1024,3072), N=2048.
//   col<1024 -> Kf frag16, col>=1024 -> Vf sigma'-frag.
// Q bid>=1024: i=(bid-1024)>>3, bx=i>>2 (0..7), by=xcd*4+(i&3);
//   A=queries_b, W=w_in rows [0,1024) -> Qf frag16.
// Layouts (unchanged):
//   Qf/Kf "frag16": chunk per (t=tok>>4, h), 1024 shorts; (token=16t+tc, d)
//     at (d>>3)*128 + tc*8 + (d&7).
//   Vf "sigma'-frag": chunk per (g32=tok>>5, h), 2048 shorts; (token=
//     32*g32+sigma'(8q+j), d) at ((td*4+q)*16 + (d&15))*8 + j, td=(d&63)>>4.
// ---------------------------------------------------------------------------
__global__ __launch_bounds__(256) void proj_gemm_kernel(
    const u16* __restrict__ inputs_b, const u16* __restrict__ queries_b,
    const u16* __restrict__ w_in_b, const float* __restrict__ b_in,
    u16* __restrict__ Kf, u16* __restrict__ Qf, u16* __restrict__ Vf)
{
    __shared__ u16 As[128 * 32];
    __shared__ u16 Ws[128 * 32];

    const int bid = blockIdx.x;
    const bool isQ = (bid >= 1024);
    const int x = bid & 7;
    int bx, by;
    if (!isQ) { int i = bid >> 3;          bx = i >> 3; by = x * 8 + (i & 7); }
    else      { int i = (bid - 1024) >> 3; bx = i >> 2; by = x * 4 + (i & 3); }

    const u16* A = isQ ? queries_b : inputs_b;
    const u16* W = w_in_b + (isQ ? 0 : (size_t)E_DIM * E_DIM);
    const float* bias = b_in + (isQ ? 0 : E_DIM);
    const int m_blk = by * 128;
    const int n_blk = bx * 128;
    const int K = E_DIM;

    const int tid = threadIdx.x;
    const int l = tid & 63;
    const int w = tid >> 6;
    const int m0 = (w & 1) * 64;
    const int n0 = (w >> 1) * 64;
    const int quad = l >> 4;
    const int c = l & 15;

    f32x4 acc[4][4];
    #pragma unroll
    for (int i = 0; i < 4; ++i)
        #pragma unroll
        for (int j = 0; j < 4; ++j)
            acc[i][j] = (f32x4){0.f, 0.f, 0.f, 0.f};

    const int srow = l >> 2;
    const int skoff = (l & 3) * 8;
    const u16* Ag1 = A + (size_t)(m_blk + w * 16 + srow) * K + skoff;
    const u16* Ag2 = A + (size_t)(m_blk + (w + 4) * 16 + srow) * K + skoff;
    const u16* Wg1 = W + (size_t)(n_blk + w * 16 + srow) * K + skoff;
    const u16* Wg2 = W + (size_t)(n_blk + (w + 4) * 16 + srow) * K + skoff;

    for (int k0 = 0; k0 < K; k0 += 32) {
        __syncthreads();
        async16(Ag1 + k0, As + (size_t)w * 512);
        async16(Ag2 + k0, As + (size_t)(w + 4) * 512);
        async16(Wg1 + k0, Ws + (size_t)w * 512);
        async16(Wg2 + k0, Ws + (size_t)(w + 4) * 512);
        __syncthreads();

        bf16x8 af[4], wf[4];
        #pragma unroll
        for (int t = 0; t < 4; ++t) {
            af[t] = *(const bf16x8*)&As[(m0 + t * 16 + c) * 32 + quad * 8];
            wf[t] = *(const bf16x8*)&Ws[(n0 + t * 16 + c) * 32 + quad * 8];
        }
        #pragma unroll
        for (int i = 0; i < 4; ++i)
            #pragma unroll
            for (int j = 0; j < 4; ++j)
                acc[i][j] = __builtin_amdgcn_mfma_f32_16x16x32_bf16(
                    af[i], wf[j], acc[i][j], 0, 0, 0);
    }

    #pragma unroll
    for (int jj = 0; jj < 4; ++jj) {
        int col = n_blk + n0 + jj * 16 + c;
        float bv = bias[col];
        if (isQ || col < 1024) {
            u16* dst = isQ ? Qf : Kf;
            int hh = col >> 6, d = col & 63;
            int dq = d >> 3, dj = d & 7;
            #pragma unroll
            for (int i = 0; i < 4; ++i) {
                int t = (m_blk + m0 + i * 16) >> 4;
                size_t base = ((size_t)(t * NH + hh)) * 1024
                            + (size_t)(dq * 16 + quad * 4) * 8 + dj;
                #pragma unroll
                for (int r = 0; r < 4; ++r)
                    dst[base + (size_t)r * 8] = f2bf(acc[i][jj][r] + bv);
            }
        } else {
            int vcol = col - 1024;
            int hv = vcol >> 6, d = vcol & 63;
            int td = d >> 4, ct = d & 15;
            #pragma unroll
            for (int i = 0; i < 4; ++i) {
                int tok = m_blk + m0 + i * 16;
                int g32 = tok >> 5;
                int jo = (tok & 16) >> 2;          // 0 or 4
                ushort4 pk;
                pk.x = f2bf(acc[i][jj][0] + bv);
                pk.y = f2bf(acc[i][jj][1] + bv);
                pk.z = f2bf(acc[i][jj][2] + bv);
                pk.w = f2bf(acc[i][jj][3] + bv);
                *(ushort4*)(Vf + ((size_t)(g32 * NH + hv)) * 2048
                            + (size_t)((td * 4 + quad) * 16 + ct) * 8 + jo) = pk;
            }
        }
    }
}

// ---------------------------------------------------------------------------
// Attention, S^T formulation; frag-ordered operands; no LDS/barriers.
// 1D grid 1024: bid = qt*128 + b*16 + h  -> bid%8 = h%8: all 8 q-tiles of a
// given (b,h) share one XCD (L2 reuse of K/V). 256 thr = 4 waves x 16 q rows.
// K/V frags register-double-buffered to hide global latency behind softmax.
// ---------------------------------------------------------------------------
struct KVfrags { bf16x8 kf[4][2]; bf16x8 vf[2][4]; };

__global__ __launch_bounds__(256) void attn_kernel(
    const u16* __restrict__ Qf, const u16* __restrict__ Kf,
    const u16* __restrict__ Vf, u16* __restrict__ Ob)
{
    const int tid = threadIdx.x;
    const int l = tid & 63;
    const int w = tid >> 6;
    const int quad = l >> 4;
    const int c = l & 15;
    const int bid = blockIdx.x;
    const int h = bid & 15;
    const int b = (bid >> 4) & 7;
    const int qt = bid >> 7;
    const int q0 = b * LQ + qt * 64 + w * 16;
    const float C1 = 0.18033688011112042f;   // (1/8)*log2(e)

    // Q B-frags (frag16 layout: fully coalesced)
    bf16x8 qf[2];
    {
        size_t qb = ((size_t)((q0 >> 4) * NH + h)) * 1024 + (size_t)l * 8;
        qf[0] = *(const bf16x8*)(Qf + qb);
        qf[1] = *(const bf16x8*)(Qf + qb + 512);
    }

    f32x4 o[4];
    #pragma unroll
    for (int td = 0; td < 4; ++td) o[td] = (f32x4){0.f, 0.f, 0.f, 0.f};
    float m_i = -1e30f, l_i = 0.f;

    auto load_kv = [&](int kv0, KVfrags& dst) {
        const int kvg = b * LKV + kv0;
        #pragma unroll
        for (int nt = 0; nt < 4; ++nt) {
            size_t kb = ((size_t)((((kvg >> 4) + nt) * NH) + h)) * 1024 + (size_t)l * 8;
            dst.kf[nt][0] = *(const bf16x8*)(Kf + kb);
            dst.kf[nt][1] = *(const bf16x8*)(Kf + kb + 512);
        }
        #pragma unroll
        for (int g = 0; g < 2; ++g) {
            size_t vb = ((size_t)((((kvg >> 5) + g) * NH) + h)) * 2048 + (size_t)l * 8;
            #pragma unroll
            for (int td = 0; td < 4; ++td)
                dst.vf[g][td] = *(const bf16x8*)(Vf + vb + td * 512);
        }
    };

    auto step = [&](KVfrags& cv) {
        // S^T = K · Q^T (4 kv-tiles of 16)
        f32x4 s[4];
        #pragma unroll
        for (int nt = 0; nt < 4; ++nt) s[nt] = (f32x4){0.f, 0.f, 0.f, 0.f};
        #pragma unroll
        for (int nt = 0; nt < 4; ++nt)
            #pragma unroll
            for (int hk = 0; hk < 2; ++hk)
                s[nt] = __builtin_amdgcn_mfma_f32_16x16x32_bf16(
                    cv.kf[nt][hk], qf[hk], s[nt], 0, 0, 0);

        // online softmax; lane state belongs to q = q0 + c (replicated / quads)
        float vm = -1e30f;
        #pragma unroll
        for (int nt = 0; nt < 4; ++nt)
            #pragma unroll
            for (int r = 0; r < 4; ++r) vm = fmaxf(vm, s[nt][r]);
        vm = fmaxf(vm, __shfl_xor(vm, 16, 64));
        vm = fmaxf(vm, __shfl_xor(vm, 32, 64));
        float mnew = fmaxf(m_i, vm);
        float alpha = __builtin_amdgcn_exp2f((m_i - mnew) * C1);
        m_i = mnew;

        float p[4][4];
        float rs = 0.f;
        #pragma unroll
        for (int nt = 0; nt < 4; ++nt)
            #pragma unroll
            for (int r = 0; r < 4; ++r) {
                p[nt][r] = __builtin_amdgcn_exp2f((s[nt][r] - mnew) * C1);
                rs += p[nt][r];
            }
        rs += __shfl_xor(rs, 16, 64);
        rs += __shfl_xor(rs, 32, 64);
        l_i = l_i * alpha + rs;

        // rescale O (O rows are q = quad*4+r; alpha lives at lane q = c)
        float ar[4];
        #pragma unroll
        for (int r = 0; r < 4; ++r) ar[r] = __shfl(alpha, quad * 4 + r, 16);
        #pragma unroll
        for (int td = 0; td < 4; ++td)
            #pragma unroll
            for (int r = 0; r < 4; ++r) o[td][r] *= ar[r];

        // A-frags for PV: sigma' puts the lane's own p regs in place
        bf16x8 af[2];
        #pragma unroll
        for (int g = 0; g < 2; ++g)
            #pragma unroll
            for (int r = 0; r < 4; ++r) {
                af[g][r]     = (short)f2bf(p[2 * g][r]);
                af[g][4 + r] = (short)f2bf(p[2 * g + 1][r]);
            }

        #pragma unroll
        for (int g = 0; g < 2; ++g)
            #pragma unroll
            for (int td = 0; td < 4; ++td)
                o[td] = __builtin_amdgcn_mfma_f32_16x16x32_bf16(
                    af[g], cv.vf[g][td], o[td], 0, 0, 0);
    };

    // software-pipelined: prefetch next 64-kv chunk while computing current
    KVfrags bufA, bufB;
    load_kv(0, bufA);
    #pragma unroll
    for (int it = 0; it < 16; it += 2) {
        if (it + 1 < 16) load_kv((it + 1) * 64, bufB);
        step(bufA);
        if (it + 2 < 16) load_kv((it + 2) * 64, bufA);
        if (it + 1 < 16) step(bufB);
    }

    // epilogue: normalize (l_i lives at lane q=c; O rows are q=quad*4+r)
    float invl = 1.f / l_i;
    float ir[4];
    #pragma unroll
    for (int r = 0; r < 4; ++r) ir[r] = __shfl(invl, quad * 4 + r, 16);
    #pragma unroll
    for (int td = 0; td < 4; ++td)
        #pragma unroll
        for (int r = 0; r < 4; ++r)
            Ob[(size_t)(q0 + quad * 4 + r) * E_DIM + h * 64 + td * 16 + c] =
                f2bf(o[td][r] * ir[r]);
}

// ---------------------------------------------------------------------------
// Output projection: out[4096,1024] = Ob @ w_out^T + b_out (fp32 out).
// 1D grid 256, XCD-compact: xcd = bid&7 -> by strip of 4, bx slow.
// ---------------------------------------------------------------------------
__global__ __launch_bounds__(256) void out_gemm_kernel(
    const u16* __restrict__ A, const u16* __restrict__ W,
    const float* __restrict__ bias, float* __restrict__ Cf)
{
    __shared__ u16 As[128 * 32];
    __shared__ u16 Ws[128 * 32];

    const int K = E_DIM, N = E_DIM;
    const int bid = blockIdx.x;
    const int x = bid & 7;
    const int i_ = bid >> 3;            // 0..31
    const int m_blk = (x * 4 + (i_ & 3)) * 128;
    const int n_blk = (i_ >> 2) * 128;

    const int tid = threadIdx.x;
    const int l = tid & 63;
    const int w = tid >> 6;
    const int m0 = (w & 1) * 64;
    const int n0 = (w >> 1) * 64;
    const int quad = l >> 4;
    const int c = l & 15;

    f32x4 acc[4][4];
    #pragma unroll
    for (int i = 0; i < 4; ++i)
        #pragma unroll
        for (int j = 0; j < 4; ++j)
            acc[i][j] = (f32x4){0.f, 0.f, 0.f, 0.f};

    const int srow = l >> 2;
    const int skoff = (l & 3) * 8;
    const u16* Ag1 = A + (size_t)(m_blk + w * 16 + srow) * K + skoff;
    const u16* Ag2 = A + (size_t)(m_blk + (w + 4) * 16 + srow) * K + skoff;
    const u16* Wg1 = W + (size_t)(n_blk + w * 16 + srow) * K + skoff;
    const u16* Wg2 = W + (size_t)(n_blk + (w + 4) * 16 + srow) * K + skoff;

    for (int k0 = 0; k0 < K; k0 += 32) {
        __syncthreads();
        async16(Ag1 + k0, As + (size_t)w * 512);
        async16(Ag2 + k0, As + (size_t)(w + 4) * 512);
        async16(Wg1 + k0, Ws + (size_t)w * 512);
        async16(Wg2 + k0, Ws + (size_t)(w + 4) * 512);
        __syncthreads();

        bf16x8 af[4], wf[4];
        #pragma unroll
        for (int t = 0; t < 4; ++t) {
            af[t] = *(const bf16x8*)&As[(m0 + t * 16 + c) * 32 + quad * 8];
            wf[t] = *(const bf16x8*)&Ws[(n0 + t * 16 + c) * 32 + quad * 8];
        }
        #pragma unroll
        for (int i = 0; i < 4; ++i)
            #pragma unroll
            for (int j = 0; j < 4; ++j)
                acc[i][j] = __builtin_amdgcn_mfma_f32_16x16x32_bf16(
                    af[i], wf[j], acc[i][j], 0, 0, 0);
    }

    #pragma unroll
    for (int j = 0; j < 4; ++j) {
        int col = n_blk + n0 + j * 16 + c;
        float bv = bias[col];
        #pragma unroll
        for (int i = 0; i < 4; ++i) {
            int row = m_blk + m0 + i * 16 + quad * 4;
            #pragma unroll
            for (int r = 0; r < 4; ++r)
                Cf[(size_t)(row + r) * N + col] = acc[i][j][r] + bv;
        }
    }
}

// ---------------------------------------------------------------------------
extern "C" void kernel_launch(void* const* d_in, const int* in_sizes, int n_in,
                              void* d_out, int out_size, void* d_ws, size_t ws_size,
                              hipStream_t stream) {
    const float* inputs  = (const float*)d_in[0];   // [8192,1024]
    const float* queries = (const float*)d_in[1];   // [4096,1024]
    const float* w_in    = (const float*)d_in[2];   // [3072,1024]
    const float* b_in    = (const float*)d_in[3];   // [3072]
    const float* w_out   = (const float*)d_in[4];   // [1024,1024]
    const float* b_out   = (const float*)d_in[5];   // [1024]
    float* out = (float*)d_out;                     // [4096,1024] fp32

    const int NQ = BSEG * LQ;    // 4096
    const int NKV = BSEG * LKV;  // 8192

    // workspace: 80 MB
    u16* inputs_b  = (u16*)d_ws;                                   // 16 MB
    u16* queries_b = inputs_b  + (size_t)NKV * E_DIM;              //  8 MB
    u16* w_in_b    = queries_b + (size_t)NQ * E_DIM;               //  6 MB
    u16* w_out_b   = w_in_b    + (size_t)3 * E_DIM * E_DIM;        //  2 MB
    u16* Qf        = w_out_b   + (size_t)E_DIM * E_DIM;            //  8 MB
    u16* Kf        = Qf        + (size_t)NQ * E_DIM;               // 16 MB
    u16* Vf        = Kf        + (size_t)NKV * E_DIM;              // 16 MB
    u16* Ob        = Vf        + (size_t)NKV * E_DIM;              //  8 MB

    dim3 blk(256);

    cvt_all_kernel<<<16384, blk, 0, stream>>>(
        inputs, queries, w_in, w_out, inputs_b, queries_b, w_in_b, w_out_b);

    proj_gemm_kernel<<<1280, blk, 0, stream>>>(
        inputs_b, queries_b, w_in_b, b_in, Kf, Qf, Vf);

    attn_kernel<<<1024, blk, 0, stream>>>(Qf, Kf, Vf, Ob);

    out_gemm_kernel<<<256, blk, 0, stream>>>(
        Ob, w_out_b, b_out, out);
}